// Round 8
// baseline (152.433 us; speedup 1.0000x reference)
//
#include <hip/hip_runtime.h>
#include <hip/hip_bf16.h>

#define M_DIM 2048   // size (logical rows)
#define MS_DIM 4096  // stacked rows (A/B interleaved)
#define K_DIM 2048   // prev_size
#define N_DIM 8192   // batch

#define BMS 256      // stacked rows per block
#define BN 256
#define BK 32
#define NT (K_DIM / BK)   // 64 K-tiles

typedef __attribute__((ext_vector_type(4))) float f32x4;
typedef __attribute__((ext_vector_type(8))) short s16x8;

static __device__ __forceinline__ ushort f2bf(float x) {
    __hip_bfloat16 h = __float2bfloat16(x);
    return *reinterpret_cast<ushort*>(&h);
}

// async global->LDS: each lane contributes 16B; LDS dest is wave-uniform base,
// hardware writes base + lane*16 (linear).
static __device__ __forceinline__ void stage1k(const ushort* g, ushort* l) {
    __builtin_amdgcn_global_load_lds(
        (const __attribute__((address_space(1))) void*)g,
        (__attribute__((address_space(3))) void*)l, 16, 0, 0);
}

// ------- softmax over rows of Wa/Wb -> interleaved bf16 probabilities -------
// Pab row 2r = softmax(Wa row r), row 2r+1 = softmax(Wb row r).
__global__ __launch_bounds__(256) void softmax_rows_kernel(
    const float* __restrict__ Wa, const float* __restrict__ Wb,
    ushort* __restrict__ Pab)
{
    const float* W = blockIdx.y ? Wb : Wa;
    const int row = blockIdx.x;
    const int t = threadIdx.x;
    const float* w = W + (size_t)row * K_DIM + t * 8;
    float4 v0 = *(const float4*)(w);
    float4 v1 = *(const float4*)(w + 4);
    float x[8] = {v0.x, v0.y, v0.z, v0.w, v1.x, v1.y, v1.z, v1.w};

    float m = x[0];
#pragma unroll
    for (int i = 1; i < 8; ++i) m = fmaxf(m, x[i]);
#pragma unroll
    for (int off = 32; off >= 1; off >>= 1) m = fmaxf(m, __shfl_xor(m, off));
    __shared__ float redm[4], reds[4];
    const int wid = t >> 6;
    if ((t & 63) == 0) redm[wid] = m;
    __syncthreads();
    m = fmaxf(fmaxf(redm[0], redm[1]), fmaxf(redm[2], redm[3]));

    float s = 0.f;
#pragma unroll
    for (int i = 0; i < 8; ++i) { x[i] = __expf(x[i] - m); s += x[i]; }
#pragma unroll
    for (int off = 32; off >= 1; off >>= 1) s += __shfl_xor(s, off);
    if ((t & 63) == 0) reds[wid] = s;
    __syncthreads();
    s = reds[0] + reds[1] + reds[2] + reds[3];
    const float inv = 1.0f / s;

    union { ushort u[8]; int4 v; } pk;
#pragma unroll
    for (int i = 0; i < 8; ++i) pk.u[i] = f2bf(x[i] * inv);
    *(int4*)(Pab + (size_t)(2 * row + blockIdx.y) * K_DIM + t * 8) = pk.v;
}

// ---------- table softmax (over 16) contracted with gate coeffs -> c[4][M] --
__global__ __launch_bounds__(256) void table_c_kernel(
    const float* __restrict__ TW, float4* __restrict__ C4)
{
    const int s = blockIdx.x * 256 + threadIdx.x;
    if (s >= M_DIM) return;
    float x[16];
    float m = -1e30f;
#pragma unroll
    for (int t = 0; t < 16; ++t) { x[t] = TW[t * M_DIM + s]; m = fmaxf(m, x[t]); }
    float sum = 0.f;
#pragma unroll
    for (int t = 0; t < 16; ++t) { x[t] = __expf(x[t] - m); sum += x[t]; }
    const float inv = 1.0f / sum;

    const float c0a[16] = {0,0,0,0,0,0,0,0, 1,1,1,1,1,1,1,1};
    const float cAa[16] = {0,0,1,1,0,0,1,1, -1,-1,0,0,-1,-1,0,0};
    const float cBa[16] = {0,0,0,0,1,1,1,1, -1,-1,-1,-1,0,0,0,0};
    const float cXa[16] = {0,1,-1,0,-1,0,-2,-1, 1,2,0,1,0,1,-1,0};
    float c0 = 0.f, cA = 0.f, cB = 0.f, cX = 0.f;
#pragma unroll
    for (int t = 0; t < 16; ++t) {
        const float p = x[t] * inv;
        c0 += p * c0a[t]; cA += p * cAa[t]; cB += p * cBa[t]; cX += p * cXa[t];
    }
    C4[s] = make_float4(c0, cA, cB, cX);
}

// ---------- prev [K][N] f32 -> prevT [N][K] bf16 (transpose + convert) ------
__global__ __launch_bounds__(256) void transp_conv_kernel(
    const float* __restrict__ src, ushort* __restrict__ dst)
{
    __shared__ ushort tile[64][72];
    const int n0 = blockIdx.x * 64;
    const int k0 = blockIdx.y * 64;
    const int t = threadIdx.x;
#pragma unroll
    for (int it = 0; it < 4; ++it) {
        const int lin = it * 256 + t;      // 0..1023
        const int k = lin >> 4;            // 0..63
        const int n4 = (lin & 15) * 4;     // 0..60
        float4 v = *(const float4*)(src + (size_t)(k0 + k) * N_DIM + n0 + n4);
        tile[n4 + 0][k] = f2bf(v.x);
        tile[n4 + 1][k] = f2bf(v.y);
        tile[n4 + 2][k] = f2bf(v.z);
        tile[n4 + 3][k] = f2bf(v.w);
    }
    __syncthreads();
#pragma unroll
    for (int it = 0; it < 2; ++it) {
        const int lin = it * 256 + t;      // 0..511
        const int n = lin >> 3;            // 0..63
        const int k8 = (lin & 7) * 8;      // 0..56
        int4 v = *(const int4*)&tile[n][k8];
        *(int4*)(dst + (size_t)(n0 + n) * K_DIM + k0 + k8) = v;
    }
}

// ---- stacked GEMM (m201 skeleton) + gate epilogue --------------------------
// Pab[4096][2048] x PrevT^T -> out pairs; block 256(stacked)x256, 8 waves
// (2x4), wave 128x64, acc[8][4] f32x4. BK=32, LDS tri-buffered (96 KB):
// stage lead = 2 tiles -> steady-state guard is counted vmcnt(4), never 0.
// Regions [256][32] bf16, 16B-slot swizzle sigma(r)=(r>>1)&3 (write side:
// pre-swizzled global col; read side: same XOR) - structural-minimum banking
// (verified 0 conflicts in R4/R5/R7).
//
// Per tile, 2 phases (m201 shape): {ds_reads for THIS phase; 2 stage calls;
// barrier; lgkm0 (+sched_barrier, rule #18); setprio; 16 MFMA; setprio;
// barrier}. Hazards: tile t staged during t-2, drained by vmcnt at ph2(t-1)
// before its barriers; stage(t+2) overwrites buf of t-1, whose last reads are
// lgkm-drained before the barrier that precedes the stage issue. Tail
// (kt >= NT-2): vmcnt(0).

#define MFMA16(MI0)                                                            \
    _Pragma("unroll") for (int mi = (MI0); mi < (MI0) + 4; ++mi)               \
    _Pragma("unroll") for (int ni = 0; ni < 4; ++ni)                           \
        acc[mi][ni] = __builtin_amdgcn_mfma_f32_16x16x32_bf16(                 \
            fa[mi], fp[ni], acc[mi][ni], 0, 0, 0);

#define STAGE_A(T, BS) if ((T) < NT) { const size_t o_ = (size_t)(T) * BK;     \
    stage1k(gA + o_,        sAflat + (BS) * 8192 + (wid * 16) * 32);           \
    stage1k(gA + half + o_, sAflat + (BS) * 8192 + (128 + wid * 16) * 32); }
#define STAGE_P(T, BS) if ((T) < NT) { const size_t o_ = (size_t)(T) * BK;     \
    stage1k(gP + o_,        sPflat + (BS) * 8192 + (wid * 16) * 32);           \
    stage1k(gP + half + o_, sPflat + (BS) * 8192 + (128 + wid * 16) * 32); }

__global__ __launch_bounds__(512, 1) void logic_gemm_kernel(
    const ushort* __restrict__ Pab,  // [4096][2048] bf16, A/B interleaved
    const ushort* __restrict__ Pt,   // prevT [8192][2048] bf16
    const float4* __restrict__ C4,   // [2048]
    float* __restrict__ out)         // [2048][8192]
{
    __shared__ ushort sA[3][256][32];   // 48 KB
    __shared__ ushort sP[3][256][32];   // 48 KB
    ushort* sAflat = &sA[0][0][0];
    ushort* sPflat = &sP[0][0][0];

    const int m0s = blockIdx.y * BMS;   // stacked row base
    const int n0  = blockIdx.x * BN;
    const int t = threadIdx.x;
    const int wid = t >> 6, lane = t & 63;
    const int wr = wid >> 2, wc = wid & 3;   // 2(Mstacked) x 4(N)
    const int lq = lane >> 4, lr = lane & 15;

    // staging: lane -> region row (lane>>2), pre-swizzled source col
    const int srow = lane >> 2;                               // 0..15
    const int scol = (((lane & 3) ^ ((lane >> 3) & 3)) << 3); // {0,8,16,24}
    const ushort* gA = Pab + (size_t)(m0s + wid * 16 + srow) * K_DIM + scol;
    const ushort* gP = Pt  + (size_t)(n0  + wid * 16 + srow) * K_DIM + scol;
    const size_t half = (size_t)128 * K_DIM;

    // ds_read byte offsets: row*64 + 16*(lq ^ sigma(row)), sigma=(lr>>1)&3
    const int cswz = (lq ^ ((lr >> 1) & 3)) << 4;
    const int roA = (wr * 128 + lr) * 64 + cswz;
    const int roP = (wc * 64 + lr) * 64 + cswz;

    f32x4 acc[8][4] = {};
    s16x8 fa[8], fp[4];

    // prologue: tiles 0,1 (8 calls); drain tile 0 (leave tile 1's 4 in flight)
    STAGE_A(0, 0); STAGE_P(0, 0);
    STAGE_A(1, 1); STAGE_P(1, 1);
    asm volatile("s_waitcnt vmcnt(4)" ::: "memory");
    __builtin_amdgcn_s_barrier();

    int bcur = 0, bstg = 2;
    for (int kt = 0; kt < NT; ++kt) {
        const char* curA = (const char*)sAflat + bcur * 16384;
        const char* curP = (const char*)sPflat + bcur * 16384;

        // ---- phase 1: mi 0..3 ----
#pragma unroll
        for (int i = 0; i < 4; ++i) fa[i] = *(const s16x8*)(curA + roA + i * 1024);
#pragma unroll
        for (int i = 0; i < 4; ++i) fp[i] = *(const s16x8*)(curP + roP + i * 1024);
        STAGE_A(kt + 2, bstg);
        __builtin_amdgcn_s_barrier();
        asm volatile("s_waitcnt lgkmcnt(0)" ::: "memory");
        __builtin_amdgcn_sched_barrier(0);
        __builtin_amdgcn_s_setprio(1);
        MFMA16(0);
        __builtin_amdgcn_s_setprio(0);
        __builtin_amdgcn_s_barrier();

        // ---- phase 2: mi 4..7 ----
#pragma unroll
        for (int i = 4; i < 8; ++i) fa[i] = *(const s16x8*)(curA + roA + i * 1024);
        STAGE_P(kt + 2, bstg);
        if (kt < NT - 2) asm volatile("s_waitcnt vmcnt(4)" ::: "memory");
        else             asm volatile("s_waitcnt vmcnt(0)" ::: "memory");
        __builtin_amdgcn_s_barrier();
        asm volatile("s_waitcnt lgkmcnt(0)" ::: "memory");
        __builtin_amdgcn_sched_barrier(0);
        __builtin_amdgcn_s_setprio(1);
        MFMA16(4);
        __builtin_amdgcn_s_setprio(0);
        __builtin_amdgcn_s_barrier();

        bcur = (bcur == 2) ? 0 : bcur + 1;
        bstg = (bstg == 2) ? 0 : bstg + 1;
    }

    // epilogue: stacked rows lq*4 + {0,1,2,3} = {A(L), B(L), A(L+1), B(L+1)}
#pragma unroll
    for (int mi = 0; mi < 8; ++mi) {
        const int sbase = m0s + wr * 128 + mi * 16 + lq * 4;  // even
        const int L = sbase >> 1;
        const float4 c0 = C4[L];
        const float4 c1 = C4[L + 1];
#pragma unroll
        for (int ni = 0; ni < 4; ++ni) {
            const int col = n0 + wc * 64 + ni * 16 + lr;
            const f32x4 v = acc[mi][ni];
            out[(size_t)L * N_DIM + col] =
                c0.x + c0.y * v[0] + c0.z * v[1] + c0.w * v[0] * v[1];
            out[(size_t)(L + 1) * N_DIM + col] =
                c1.x + c1.y * v[2] + c1.z * v[3] + c1.w * v[2] * v[3];
        }
    }
}

extern "C" void kernel_launch(void* const* d_in, const int* in_sizes, int n_in,
                              void* d_out, int out_size, void* d_ws, size_t ws_size,
                              hipStream_t stream) {
    const float* prev = (const float*)d_in[0];   // [2048][8192]
    const float* Wa   = (const float*)d_in[1];   // [2048][2048]
    const float* Wb   = (const float*)d_in[2];   // [2048][2048]
    const float* TW   = (const float*)d_in[3];   // [16][2048]
    float* out = (float*)d_out;                  // [2048][8192]

    char* ws = (char*)d_ws;
    ushort* Pab = (ushort*)(ws);                         // 16 MiB (interleaved)
    ushort* Pt  = (ushort*)(ws + (size_t)(16u << 20));   // 32 MiB
    float4* C4  = (float4*)(ws + (size_t)(48u << 20));   // 32 KiB

    softmax_rows_kernel<<<dim3(2048, 2), 256, 0, stream>>>(Wa, Wb, Pab);
    table_c_kernel<<<dim3(8), 256, 0, stream>>>(TW, C4);
    transp_conv_kernel<<<dim3(N_DIM / 64, K_DIM / 64), 256, 0, stream>>>(prev, Pt);
    logic_gemm_kernel<<<dim3(N_DIM / BN, MS_DIM / BMS), 512, 0, stream>>>(Pab, Pt, C4, out);
}

// Round 9
// 91.983 us; speedup vs baseline: 1.6572x; 1.6572x over previous
//
#include <hip/hip_runtime.h>
#include <hip/hip_bf16.h>

#define M_DIM 2048   // size
#define K_DIM 2048   // prev_size
#define N_DIM 8192   // batch

#define BM 128
#define BN 256
#define BK 128            // i8 elements per K-tile (two kh halves of 64)
#define NT (K_DIM / BK)   // 16 K-tiles

typedef __attribute__((ext_vector_type(4))) int i32x4;

// async global->LDS: each lane contributes 16B; LDS dest is wave-uniform base,
// hardware writes base + lane*16 (linear).
static __device__ __forceinline__ void stage1k(const unsigned char* g, void* l) {
    __builtin_amdgcn_global_load_lds(
        (const __attribute__((address_space(1))) void*)g,
        (__attribute__((address_space(3))) void*)l, 16, 0, 0);
}

// ---- softmax over rows of Wa/Wb -> u8 quantized probs + per-row scale ------
// a_k = round(127 * exp(x_k - m)); dequant: p_k = a_k / (127 * s).
// Row scale S = 1/(127*127*s) folds both 127s for the dot-product dequant.
__global__ __launch_bounds__(256) void softmax_rows_kernel(
    const float* __restrict__ Wa, const float* __restrict__ Wb,
    unsigned char* __restrict__ Pa, unsigned char* __restrict__ Pb,
    float* __restrict__ SA, float* __restrict__ SB)
{
    const float* W = blockIdx.y ? Wb : Wa;
    unsigned char* P = blockIdx.y ? Pb : Pa;
    float* S = blockIdx.y ? SB : SA;
    const int row = blockIdx.x;
    const int t = threadIdx.x;
    const float* w = W + (size_t)row * K_DIM + t * 8;
    float4 v0 = *(const float4*)(w);
    float4 v1 = *(const float4*)(w + 4);
    float x[8] = {v0.x, v0.y, v0.z, v0.w, v1.x, v1.y, v1.z, v1.w};

    float m = x[0];
#pragma unroll
    for (int i = 1; i < 8; ++i) m = fmaxf(m, x[i]);
#pragma unroll
    for (int off = 32; off >= 1; off >>= 1) m = fmaxf(m, __shfl_xor(m, off));
    __shared__ float redm[4], reds[4];
    const int wid = t >> 6;
    if ((t & 63) == 0) redm[wid] = m;
    __syncthreads();
    m = fmaxf(fmaxf(redm[0], redm[1]), fmaxf(redm[2], redm[3]));

    float s = 0.f;
#pragma unroll
    for (int i = 0; i < 8; ++i) { x[i] = __expf(x[i] - m); s += x[i]; }
#pragma unroll
    for (int off = 32; off >= 1; off >>= 1) s += __shfl_xor(s, off);
    if ((t & 63) == 0) reds[wid] = s;
    __syncthreads();
    s = reds[0] + reds[1] + reds[2] + reds[3];

    union { unsigned char u[8]; int2 v; } pk;
#pragma unroll
    for (int i = 0; i < 8; ++i)
        pk.u[i] = (unsigned char)(int)(127.f * x[i] + 0.5f);
    *(int2*)(P + (size_t)row * K_DIM + t * 8) = pk.v;
    if (t == 0) S[row] = 1.f / (16129.f * s);
}

// ---------- table softmax (over 16) contracted with gate coeffs -> c[4][M] --
__global__ __launch_bounds__(256) void table_c_kernel(
    const float* __restrict__ TW, float4* __restrict__ C4)
{
    const int s = blockIdx.x * 256 + threadIdx.x;
    if (s >= M_DIM) return;
    float x[16];
    float m = -1e30f;
#pragma unroll
    for (int t = 0; t < 16; ++t) { x[t] = TW[t * M_DIM + s]; m = fmaxf(m, x[t]); }
    float sum = 0.f;
#pragma unroll
    for (int t = 0; t < 16; ++t) { x[t] = __expf(x[t] - m); sum += x[t]; }
    const float inv = 1.0f / sum;

    const float c0a[16] = {0,0,0,0,0,0,0,0, 1,1,1,1,1,1,1,1};
    const float cAa[16] = {0,0,1,1,0,0,1,1, -1,-1,0,0,-1,-1,0,0};
    const float cBa[16] = {0,0,0,0,1,1,1,1, -1,-1,-1,-1,0,0,0,0};
    const float cXa[16] = {0,1,-1,0,-1,0,-2,-1, 1,2,0,1,0,1,-1,0};
    float c0 = 0.f, cA = 0.f, cB = 0.f, cX = 0.f;
#pragma unroll
    for (int t = 0; t < 16; ++t) {
        const float p = x[t] * inv;
        c0 += p * c0a[t]; cA += p * cAa[t]; cB += p * cBa[t]; cX += p * cXa[t];
    }
    C4[s] = make_float4(c0, cA, cB, cX);
}

// ---- prev [K][N] f32 -> prevT [N][K] u8 (transpose + quantize x127) --------
__global__ __launch_bounds__(256) void transp_conv_kernel(
    const float* __restrict__ src, unsigned char* __restrict__ dst)
{
    __shared__ unsigned char tile[64][64];   // stride 64 -> 16B-aligned chunks
    const int n0 = blockIdx.x * 64;
    const int k0 = blockIdx.y * 64;
    const int t = threadIdx.x;
#pragma unroll
    for (int it = 0; it < 4; ++it) {
        const int lin = it * 256 + t;      // 0..1023
        const int k = lin >> 4;            // 0..63
        const int n4 = (lin & 15) * 4;     // 0..60
        float4 v = *(const float4*)(src + (size_t)(k0 + k) * N_DIM + n0 + n4);
        tile[n4 + 0][k] = (unsigned char)(int)(127.f * v.x + 0.5f);
        tile[n4 + 1][k] = (unsigned char)(int)(127.f * v.y + 0.5f);
        tile[n4 + 2][k] = (unsigned char)(int)(127.f * v.z + 0.5f);
        tile[n4 + 3][k] = (unsigned char)(int)(127.f * v.w + 0.5f);
    }
    __syncthreads();
    const int n = t >> 2;                  // 0..63
    const int k16 = (t & 3) * 16;          // 0..48
    int4 v = *(const int4*)&tile[n][k16];
    *(int4*)(dst + (size_t)(n0 + n) * K_DIM + k0 + k16) = v;
}

// ------------- dual i8 GEMM, pipelined 4-phase schedule + gate epilogue -----
// Byte-identical structure to the verified R7 bf16 kernel (121 us, 0 bank
// conflicts): LDS regions [128 or 256 rows][64 B], sigma(r)=(r>>1)&3 16B-slot
// swizzle (write: pre-swizzled global col; read: same XOR), same stage-pair /
// barrier / vmcnt ledger. A "tile" now covers K=128 i8 (region row = 64 i8),
// so NT = 16: MFMA count, LDS traffic, staged bytes, and barriers all halve.
// MFMA: mfma_i32_16x16x64_i8 - per-lane 16B = 16 contiguous K bytes at
// row = lane&15, kgroup = lane>>4 (same 16B/lane mapping as bf16 16x16x32);
// C/D layout dtype-independent (m121).
//
// Stage pairs (2 loads each) for tile T:
//   A(T)@ph2(T-2), B(T)@ph3(T-2), C(T)@ph4(T-2), D(T)@ph1(T-1)
// Guards: vmcnt(6) at ph1 (drains D(t)), vmcnt(6) at ph3 (drains A,B(t+1)).
// Tail (kt >= NT-2): vmcnt(0).

#define MFMA8(ACC, FA, FP, MI0)                                                \
    _Pragma("unroll") for (int mi = (MI0); mi < (MI0) + 2; ++mi)               \
    _Pragma("unroll") for (int ni = 0; ni < 4; ++ni)                           \
        ACC[mi][ni] = __builtin_amdgcn_mfma_i32_16x16x64_i8(                   \
            FA[mi], FP[ni], ACC[mi][ni], 0, 0, 0);

#define STAGE_A(T) do { const int b_ = (T) & 1; const size_t o_ = (size_t)(T) * BK; \
    stage1k(gPa + o_,  &sPa[b_][0][wid * 16][0]);                              \
    stage1k(gPt0 + o_, &sPt[b_][0][wid * 16][0]); } while (0)
#define STAGE_B(T) do { const int b_ = (T) & 1; const size_t o_ = (size_t)(T) * BK; \
    stage1k(gPt1 + o_, &sPt[b_][0][128 + wid * 16][0]);                        \
    stage1k(gPb + o_,  &sPb[b_][0][wid * 16][0]); } while (0)
#define STAGE_C(T) do { const int b_ = (T) & 1; const size_t o_ = (size_t)(T) * BK + 64; \
    stage1k(gPa + o_,  &sPa[b_][1][wid * 16][0]);                              \
    stage1k(gPt0 + o_, &sPt[b_][1][wid * 16][0]); } while (0)
#define STAGE_D(T) do { const int b_ = (T) & 1; const size_t o_ = (size_t)(T) * BK + 64; \
    stage1k(gPt1 + o_, &sPt[b_][1][128 + wid * 16][0]);                        \
    stage1k(gPb + o_,  &sPb[b_][1][wid * 16][0]); } while (0)

__global__ __launch_bounds__(512, 2) void logic_gemm_kernel(
    const unsigned char* __restrict__ Pa,   // [M][K] u8
    const unsigned char* __restrict__ Pb,   // [M][K] u8
    const unsigned char* __restrict__ Pt,   // prevT [N][K] u8
    const float4* __restrict__ C4,          // [M]
    const float* __restrict__ SA,           // [M] dequant scales
    const float* __restrict__ SB,           // [M]
    float* __restrict__ out)                // [M][N]
{
    __shared__ unsigned char sPa[2][2][128][64];   // 32 KB
    __shared__ unsigned char sPb[2][2][128][64];   // 32 KB
    __shared__ unsigned char sPt[2][2][256][64];   // 64 KB

    const int m0 = blockIdx.y * BM;
    const int n0 = blockIdx.x * BN;
    const int t = threadIdx.x;
    const int wid = t >> 6, lane = t & 63;
    const int wr = wid >> 2, wc = wid & 3;   // 2M x 4N waves, 64x64 out each
    const int lq = lane >> 4, lr = lane & 15;

    // staging: lane -> region row (lane>>2), pre-swizzled source col (bytes)
    const int srow = lane >> 2;                               // 0..15
    const int scol = (((lane & 3) ^ ((lane >> 3) & 3)) << 4); // {0,16,32,48} B
    const unsigned char* gPa  = Pa + (size_t)(m0 + wid * 16 + srow) * K_DIM + scol;
    const unsigned char* gPb  = Pb + (size_t)(m0 + wid * 16 + srow) * K_DIM + scol;
    const unsigned char* gPt0 = Pt + (size_t)(n0 + wid * 16 + srow) * K_DIM + scol;
    const unsigned char* gPt1 = gPt0 + (size_t)128 * K_DIM;

    // ds_read byte offsets (swizzled): row*64 + 16*(lq ^ sigma(row)),
    // sigma(r) = (r>>1)&3 -> conflict-free (verified R4/R5/R7: conflicts = 0)
    const int cswz = (lq ^ ((lr >> 1) & 3)) << 4;
    const int roA = (wr * 64 + lr) * 64 + cswz;   // within [128][64B] region
    const int roP = (wc * 64 + lr) * 64 + cswz;   // within [256][64B] region

    i32x4 accA[4][4] = {};
    i32x4 accB[4][4] = {};
    i32x4 fX0[4], fX1[4], fpA[4], fpB[4];

    // prologue: A,B,C,D(0), A,B,C(1) = 14 loads; drain first 4 (A,B(0));
    // barrier; pre-read tile-0 kh0 fragments.
    STAGE_A(0); STAGE_B(0); STAGE_C(0); STAGE_D(0);
    STAGE_A(1); STAGE_B(1); STAGE_C(1);
    asm volatile("s_waitcnt vmcnt(10)" ::: "memory");
    __builtin_amdgcn_s_barrier();
#pragma unroll
    for (int i = 0; i < 4; ++i)
        fX0[i] = *(const i32x4*)((const char*)&sPa[0][0][0][0] + roA + i * 1024);
#pragma unroll
    for (int i = 0; i < 4; ++i)
        fpA[i] = *(const i32x4*)((const char*)&sPt[0][0][0][0] + roP + i * 1024);

    for (int kt = 0; kt < NT; ++kt) {
        const int buf = kt & 1;
        const char* bA1 = (const char*)&sPa[buf][1][0][0];
        const char* bB0 = (const char*)&sPb[buf][0][0][0];
        const char* bB1 = (const char*)&sPb[buf][1][0][0];
        const char* bP1 = (const char*)&sPt[buf][1][0][0];
        const char* nA0 = (const char*)&sPa[buf ^ 1][0][0][0];
        const char* nP0 = (const char*)&sPt[buf ^ 1][0][0][0];

        // -------- phase 1: accA x kh0 (uses fX0, fpA) --------
        __builtin_amdgcn_s_setprio(1);
        MFMA8(accA, fX0, fpA, 0);
        __builtin_amdgcn_s_setprio(0);
        if (kt < NT - 2) asm volatile("s_waitcnt vmcnt(6)" ::: "memory");
        else             asm volatile("s_waitcnt vmcnt(0)" ::: "memory");
#pragma unroll
        for (int i = 0; i < 4; ++i) fX1[i] = *(const i32x4*)(bB0 + roA + i * 1024);
        if (kt + 1 < NT) STAGE_D(kt + 1);
        __builtin_amdgcn_s_setprio(1);
        MFMA8(accA, fX0, fpA, 2);
        __builtin_amdgcn_s_setprio(0);
        __builtin_amdgcn_s_barrier();

        // -------- phase 2: accB x kh0 (uses fX1, fpA) --------
        __builtin_amdgcn_s_setprio(1);
        MFMA8(accB, fX1, fpA, 0);
        __builtin_amdgcn_s_setprio(0);
#pragma unroll
        for (int i = 0; i < 4; ++i) fX0[i] = *(const i32x4*)(bA1 + roA + i * 1024);
#pragma unroll
        for (int i = 0; i < 4; ++i) fpB[i] = *(const i32x4*)(bP1 + roP + i * 1024);
        if (kt + 2 < NT) STAGE_A(kt + 2);
        __builtin_amdgcn_s_setprio(1);
        MFMA8(accB, fX1, fpA, 2);
        __builtin_amdgcn_s_setprio(0);
        __builtin_amdgcn_s_barrier();

        // -------- phase 3: accA x kh1 (uses fX0, fpB) --------
        __builtin_amdgcn_s_setprio(1);
        MFMA8(accA, fX0, fpB, 0);
        __builtin_amdgcn_s_setprio(0);
        if (kt < NT - 2) asm volatile("s_waitcnt vmcnt(6)" ::: "memory");
        else             asm volatile("s_waitcnt vmcnt(0)" ::: "memory");
#pragma unroll
        for (int i = 0; i < 4; ++i) fX1[i] = *(const i32x4*)(bB1 + roA + i * 1024);
        if (kt + 2 < NT) STAGE_B(kt + 2);
        __builtin_amdgcn_s_setprio(1);
        MFMA8(accA, fX0, fpB, 2);
        __builtin_amdgcn_s_setprio(0);
        __builtin_amdgcn_s_barrier();

        // -------- phase 4: accB x kh1 (uses fX1, fpB) --------
        __builtin_amdgcn_s_setprio(1);
        MFMA8(accB, fX1, fpB, 0);
        __builtin_amdgcn_s_setprio(0);
#pragma unroll
        for (int i = 0; i < 4; ++i) fX0[i] = *(const i32x4*)(nA0 + roA + i * 1024);
#pragma unroll
        for (int i = 0; i < 4; ++i) fpA[i] = *(const i32x4*)(nP0 + roP + i * 1024);
        if (kt + 2 < NT) STAGE_C(kt + 2);
        __builtin_amdgcn_s_setprio(1);
        MFMA8(accB, fX1, fpB, 2);
        __builtin_amdgcn_s_setprio(0);
        __builtin_amdgcn_s_barrier();
    }

    // epilogue: dequant + gate polynomial
#pragma unroll
    for (int mi = 0; mi < 4; ++mi) {
#pragma unroll
        for (int i = 0; i < 4; ++i) {
            const int row = m0 + wr * 64 + mi * 16 + lq * 4 + i;
            const float4 c = C4[row];
            const float sa = SA[row];
            const float sb = SB[row];
#pragma unroll
            for (int ni = 0; ni < 4; ++ni) {
                const int col = n0 + wc * 64 + ni * 16 + lr;
                const float Av = (float)accA[mi][ni][i] * sa;
                const float Bv = (float)accB[mi][ni][i] * sb;
                out[(size_t)row * N_DIM + col] = c.x + c.y * Av + c.z * Bv + c.w * Av * Bv;
            }
        }
    }
}

extern "C" void kernel_launch(void* const* d_in, const int* in_sizes, int n_in,
                              void* d_out, int out_size, void* d_ws, size_t ws_size,
                              hipStream_t stream) {
    const float* prev = (const float*)d_in[0];   // [2048][8192]
    const float* Wa   = (const float*)d_in[1];   // [2048][2048]
    const float* Wb   = (const float*)d_in[2];   // [2048][2048]
    const float* TW   = (const float*)d_in[3];   // [16][2048]
    float* out = (float*)d_out;                  // [2048][8192]

    char* ws = (char*)d_ws;
    unsigned char* Pa = (unsigned char*)(ws);                       //  4 MiB
    unsigned char* Pb = (unsigned char*)(ws + (size_t)(4u << 20));  //  4 MiB
    unsigned char* Pt = (unsigned char*)(ws + (size_t)(8u << 20));  // 16 MiB
    float4* C4 = (float4*)(ws + (size_t)(24u << 20));               // 32 KiB
    float*  SA = (float*)(ws + (size_t)(24u << 20) + (32u << 10));  //  8 KiB
    float*  SB = (float*)(ws + (size_t)(24u << 20) + (64u << 10));  //  8 KiB

    softmax_rows_kernel<<<dim3(2048, 2), 256, 0, stream>>>(Wa, Wb, Pa, Pb, SA, SB);
    table_c_kernel<<<dim3(8), 256, 0, stream>>>(TW, C4);
    transp_conv_kernel<<<dim3(N_DIM / 64, K_DIM / 64), 256, 0, stream>>>(prev, Pt);
    logic_gemm_kernel<<<dim3(N_DIM / BN, M_DIM / BM), 512, 0, stream>>>(Pa, Pb, Pt, C4, SA, SB, out);
}